// Round 1
// baseline (693.721 us; speedup 1.0000x reference)
//
#include <hip/hip_runtime.h>
#include <hip/hip_bf16.h>
#include <math.h>

#define E_EDGES 1000000
#define LN_EPS  1e-5f

typedef unsigned short u16;
typedef __bf16 bf16x8 __attribute__((ext_vector_type(8)));
typedef float  f32x4  __attribute__((ext_vector_type(4)));

// Wave-local LDS ordering: all waves are independent; cross-lane LDS
// visibility within one wave only needs lgkmcnt(0). sched_barrier on both
// sides pins compiler scheduling (guide rule #18).
#define WAVE_SYNC() do {                                      \
    __builtin_amdgcn_sched_barrier(0);                        \
    asm volatile("s_waitcnt lgkmcnt(0)" ::: "memory");        \
    __builtin_amdgcn_sched_barrier(0);                        \
} while (0)

__device__ __forceinline__ float lo2f(unsigned d) {
    union { unsigned u; float f; } v; v.u = d << 16; return v.f;
}
__device__ __forceinline__ float hi2f(unsigned d) {
    union { unsigned u; float f; } v; v.u = d & 0xffff0000u; return v.f;
}
__device__ __forceinline__ float bf2f(u16 u) {
    union { unsigned u; float f; } v; v.u = ((unsigned)u) << 16; return v.f;
}
__device__ __forceinline__ unsigned pk2(float lo, float hi) {
    __hip_bfloat162 h = __float22bfloat162_rn(make_float2(lo, hi));
    unsigned r; __builtin_memcpy(&r, &h, 4); return r;
}

// ---------------------------------------------------------------------------
// Weight -> bf16 MFMA B-fragment conversion (one-time, ~132 KB).
// NEW layout for mfma_f32_16x16x32_bf16: lane l supplies col = l&15,
// k = 8*(l>>4) + i.  Fragment row index within a region: (ks*NT + nt)*64 + l.
// slots 0..7679  : layers 1..3, [10 ks][4 nt][64]   (2560 rows per layer)
// slots 7680..8191: layer0 (K pad 55->64), [2 ks][4 nt][64]
// slots 8192..8447: cw1 head, [2 ks][2 nt][64]
// ---------------------------------------------------------------------------
__global__ __launch_bounds__(256) void wconv_kernel(
    const float* __restrict__ wr, const float* __restrict__ w0,
    const float* __restrict__ cw1, u16* __restrict__ wf)
{
    const int s = blockIdx.x * 256 + threadIdx.x;   // 0..8447
    if (s >= 8448) return;
    const int l    = s & 63;
    const int colb = l & 15;
    const int k0   = (l >> 4) * 8;
    uint4 pk;
    if (s < 3 * 2560) {
        const int L  = s / 2560;
        const int sl = s % 2560;
        const int ks = sl >> 8;              // 0..9
        const int nt = (sl >> 6) & 3;        // 0..3
        const int k  = 32 * ks + k0;
        const int col = nt * 16 + colb;
        const float* W = wr + L * 320 * 64;
        pk.x = pk2(W[(k+0)*64+col], W[(k+1)*64+col]);
        pk.y = pk2(W[(k+2)*64+col], W[(k+3)*64+col]);
        pk.z = pk2(W[(k+4)*64+col], W[(k+5)*64+col]);
        pk.w = pk2(W[(k+6)*64+col], W[(k+7)*64+col]);
    } else if (s < 8192) {
        const int sl = s - 3 * 2560;         // 0..511
        const int ks = sl >> 8;              // 0..1
        const int nt = (sl >> 6) & 3;
        const int k  = 32 * ks + k0;
        const int col = nt * 16 + colb;
        float v[8];
        #pragma unroll
        for (int p = 0; p < 8; ++p) v[p] = (k + p < 55) ? w0[(k+p)*64 + col] : 0.f;
        pk.x = pk2(v[0],v[1]); pk.y = pk2(v[2],v[3]);
        pk.z = pk2(v[4],v[5]); pk.w = pk2(v[6],v[7]);
    } else {                                 // cw1 frags (N=32)
        const int sl = s - 8192;             // 0..255
        const int ks = sl >> 7;              // 0..1
        const int nt = (sl >> 6) & 1;
        const int k  = 32 * ks + k0;
        const int col = nt * 16 + colb;
        pk.x = pk2(cw1[(k+0)*32+col], cw1[(k+1)*32+col]);
        pk.y = pk2(cw1[(k+2)*32+col], cw1[(k+3)*32+col]);
        pk.z = pk2(cw1[(k+4)*32+col], cw1[(k+5)*32+col]);
        pk.w = pk2(cw1[(k+6)*32+col], cw1[(k+7)*32+col]);
    }
    *(uint4*)&wf[(size_t)s * 8] = pk;
}

// ---------------------------------------------------------------------------
// xprep: x fp32[E][11] (44 B rows) -> xc bf16[E][16] (32 B rows, aligned).
// ---------------------------------------------------------------------------
__global__ __launch_bounds__(256) void xprep_kernel(
    const float* __restrict__ x, u16* __restrict__ xc)
{
    __shared__ float xs[2816];                  // 256 edges * 11 floats
    const int t = threadIdx.x;
    const long long i0 = (long long)blockIdx.x * 704;   // float4 base
    #pragma unroll
    for (int k = 0; k < 3; ++k) {
        const int idx = t + k * 256;
        if (idx < 704 && i0 + idx < 2750000)
            *(float4*)&xs[idx * 4] = ((const float4*)x)[i0 + idx];
    }
    __syncthreads();
    const size_t e = (size_t)blockIdx.x * 256 + t;
    if (e < E_EDGES) {
        const float* r = &xs[t * 11];
        uint4 o0, o1;
        o0.x = pk2(r[0], r[1]);  o0.y = pk2(r[2], r[3]);
        o0.z = pk2(r[4], r[5]);  o0.w = pk2(r[6], r[7]);
        o1.x = pk2(r[8], r[9]);  o1.y = pk2(r[10], 0.f);
        o1.z = 0u;               o1.w = 0u;
        *(uint4*)&xc[e * 16]     = o0;
        *(uint4*)&xc[e * 16 + 8] = o1;
    }
}

// ---------------------------------------------------------------------------
// Layer 0: per-wave 16-edge tile, 16x16x32 MFMA, ZERO block barriers.
// Per-wave LDS region 2304 u16: raw[16][5][16] (1280) + afrag[2][64][8] (1024).
// ebuf (16 x 67 f32 = 4288 B) reuses the region after MFMA reads complete.
// ---------------------------------------------------------------------------
__global__ __launch_bounds__(256, 4) void layer0_mfma(
    const u16* __restrict__ xc, const int* __restrict__ nbr,
    const u16* __restrict__ wf0, const float* __restrict__ bias,
    const float* __restrict__ lng, const float* __restrict__ lnb,
    u16* __restrict__ xout)
{
    __shared__ u16 lds[4 * 2304];            // 18.4 KB
    const int t  = threadIdx.x;
    const int l  = t & 63;
    const int wv = t >> 6;
    u16* raw = lds + wv * 2304;
    u16* aw  = raw + 1280;
    const int el = l >> 2, cq = l & 3;
    const int e0w = blockIdx.x * 64 + wv * 16;

    {   // ---- gather: 4 threads/edge, thread cq loads neighbor row cq ----
        const size_t e = (size_t)e0w + el;
        const int4 n = *(const int4*)(nbr + 4 * e);
        const int nj = (cq == 0) ? n.x : (cq == 1) ? n.y : (cq == 2) ? n.z : n.w;
        const u16* nr = xc + (size_t)nj * 16;
        u16* dst = raw + (el * 5 + 1 + cq) * 16;
        *(uint4*)dst       = *(const uint4*)nr;
        *(uint4*)(dst + 8) = *(const uint4*)(nr + 8);
        if (cq == 0) {
            const u16* xr = xc + e * 16;
            u16* od = raw + el * 5 * 16;
            *(uint4*)od       = *(const uint4*)xr;
            *(uint4*)(od + 8) = *(const uint4*)(nr - nr + xr + 8);
        }
    }
    WAVE_SYNC();

    {   // ---- feature build: thread (el,cq) owns k-range [cq*16, cq*16+16) ----
        const u16* R = raw + el * 80;
        float f[16];
        if (cq == 0) {            // k0..10: x ; k11..15: |a-c|[0..4]
            #pragma unroll
            for (int i = 0; i < 11; ++i) f[i] = bf2f(R[i]);
            #pragma unroll
            for (int i = 0; i < 5; ++i) f[11+i] = fabsf(bf2f(R[16+i]) - bf2f(R[48+i]));
        } else if (cq == 1) {     // k16..21: |a-c|[5..10] ; k22..31: a+c[0..9]
            #pragma unroll
            for (int i = 0; i < 6; ++i) f[i] = fabsf(bf2f(R[16+5+i]) - bf2f(R[48+5+i]));
            #pragma unroll
            for (int i = 0; i < 10; ++i) f[6+i] = bf2f(R[16+i]) + bf2f(R[48+i]);
        } else if (cq == 2) {     // k32: a+c[10]; k33..43: |b-d|; k44..47: b+d[0..3]
            f[0] = bf2f(R[16+10]) + bf2f(R[48+10]);
            #pragma unroll
            for (int i = 0; i < 11; ++i) f[1+i] = fabsf(bf2f(R[32+i]) - bf2f(R[64+i]));
            #pragma unroll
            for (int i = 0; i < 4; ++i) f[12+i] = bf2f(R[32+i]) + bf2f(R[64+i]);
        } else {                  // k48..54: b+d[4..10]; pad
            #pragma unroll
            for (int i = 0; i < 7; ++i) f[i] = bf2f(R[32+4+i]) + bf2f(R[64+4+i]);
            #pragma unroll
            for (int i = 7; i < 16; ++i) f[i] = 0.f;
        }
        // frag slot: ks = cq>>1, q = 2*(cq&1)+h, row = el
        const int base = (cq >> 1) * 64 + (cq & 1) * 32 + el;
        #pragma unroll
        for (int h = 0; h < 2; ++h) {
            uint4 pk;
            pk.x = pk2(f[h*8+0], f[h*8+1]);
            pk.y = pk2(f[h*8+2], f[h*8+3]);
            pk.z = pk2(f[h*8+4], f[h*8+5]);
            pk.w = pk2(f[h*8+6], f[h*8+7]);
            *(uint4*)(aw + (size_t)(base + h * 16) * 8) = pk;
        }
    }
    WAVE_SYNC();

    f32x4 ac0 = {}, ac1 = {}, ac2 = {}, ac3 = {};
    #pragma unroll
    for (int ks = 0; ks < 2; ++ks) {
        const bf16x8 a8 = *(const bf16x8*)(aw + (size_t)(ks * 64 + l) * 8);
        const u16* bk = wf0 + (size_t)(ks * 256 + l) * 8;
        ac0 = __builtin_amdgcn_mfma_f32_16x16x32_bf16(a8, *(const bf16x8*)(bk       ), ac0, 0, 0, 0);
        ac1 = __builtin_amdgcn_mfma_f32_16x16x32_bf16(a8, *(const bf16x8*)(bk +  512), ac1, 0, 0, 0);
        ac2 = __builtin_amdgcn_mfma_f32_16x16x32_bf16(a8, *(const bf16x8*)(bk + 1024), ac2, 0, 0, 0);
        ac3 = __builtin_amdgcn_mfma_f32_16x16x32_bf16(a8, *(const bf16x8*)(bk + 1536), ac3, 0, 0, 0);
    }
    WAVE_SYNC();   // A-frag reads drained before ebuf overwrites the region

    float* ew = (float*)raw;                 // 16 x 67 f32
    const int colb = l & 15, rb = (l >> 4) * 4;
    {
        const float b0 = bias[colb],      b1 = bias[16 + colb];
        const float b2 = bias[32 + colb], b3 = bias[48 + colb];
        #pragma unroll
        for (int r = 0; r < 4; ++r) {
            float* er = ew + (rb + r) * 67;
            er[colb]      = ac0[r] + b0;  er[16 + colb] = ac1[r] + b1;
            er[32 + colb] = ac2[r] + b2;  er[48 + colb] = ac3[r] + b3;
        }
    }
    WAVE_SYNC();

    {   // ---- LN + ReLU -> xout ----
        const float* rp = ew + el * 67 + cq * 16;
        float v[16];
        float s = 0.f, qs = 0.f;
        #pragma unroll
        for (int i = 0; i < 16; ++i) { v[i] = rp[i]; s += v[i]; qs += v[i] * v[i]; }
        s  += __shfl_xor(s, 1);  s  += __shfl_xor(s, 2);
        qs += __shfl_xor(qs, 1); qs += __shfl_xor(qs, 2);
        const float mu   = s * (1.f / 64.f);
        const float var  = qs * (1.f / 64.f) - mu * mu;
        const float rinv = rsqrtf(var + LN_EPS);
        const size_t e   = (size_t)e0w + el;
        u16* outp        = xout + e * 64 + cq * 16;
        #pragma unroll
        for (int h = 0; h < 2; ++h) {
            uint4 o; unsigned* op = (unsigned*)&o;
            #pragma unroll
            for (int i = 0; i < 4; ++i) {
                const int ci = cq * 16 + h * 8 + i * 2;
                const float y0 = fmaxf(fmaf((v[h*8+i*2]   - mu) * rinv, lng[ci],   lnb[ci]),   0.f);
                const float y1 = fmaxf(fmaf((v[h*8+i*2+1] - mu) * rinv, lng[ci+1], lnb[ci+1]), 0.f);
                op[i] = pk2(y0, y1);
            }
            *(uint4*)(outp + h * 8) = o;
        }
    }
}

// ---------------------------------------------------------------------------
// Gather + feature-pack into a per-wave A-fragment region (16x16x32 layout).
// Thread (el,cq) covers k-range [cq*16, cq*16+16) of every feature block g;
// frag slot = ks*64 + q*16 + el with ks = 2g + (cq>>1), q = 2*(cq&1)+h.
// ---------------------------------------------------------------------------
__device__ __forceinline__ void gather_pack16(
    const u16* __restrict__ xin, const int* __restrict__ nbr,
    u16* __restrict__ aw, int e0w, int el, int cq, uint4& xv0, uint4& xv1)
{
    const size_t e = (size_t)e0w + el;
    const int4 n = *(const int4*)(nbr + 4 * e);
    const u16* xr = xin + e * 64           + cq * 16;
    const u16* ar = xin + (size_t)n.x * 64 + cq * 16;
    const u16* br = xin + (size_t)n.y * 64 + cq * 16;
    const u16* cr = xin + (size_t)n.z * 64 + cq * 16;
    const u16* dr = xin + (size_t)n.w * 64 + cq * 16;
    xv0 = *(const uint4*)(xr);                 xv1 = *(const uint4*)(xr + 8);
    const uint4 av0 = *(const uint4*)(ar);     const uint4 av1 = *(const uint4*)(ar + 8);
    const uint4 bv0 = *(const uint4*)(br);     const uint4 bv1 = *(const uint4*)(br + 8);
    const uint4 cv0 = *(const uint4*)(cr);     const uint4 cv1 = *(const uint4*)(cr + 8);
    const uint4 dv0 = *(const uint4*)(dr);     const uint4 dv1 = *(const uint4*)(dr + 8);
    const int base = (cq >> 1) * 64 + (cq & 1) * 32 + el;
    #pragma unroll
    for (int h = 0; h < 2; ++h) {
        const uint4 xv = h ? xv1 : xv0;
        const uint4 av = h ? av1 : av0;
        const uint4 bv = h ? bv1 : bv0;
        const uint4 cv = h ? cv1 : cv0;
        const uint4 dv = h ? dv1 : dv0;
        uint4 g1, g2, g3, g4;
        const unsigned* ap = (const unsigned*)&av;
        const unsigned* bp = (const unsigned*)&bv;
        const unsigned* cp = (const unsigned*)&cv;
        const unsigned* dp = (const unsigned*)&dv;
        unsigned* g1p = (unsigned*)&g1; unsigned* g2p = (unsigned*)&g2;
        unsigned* g3p = (unsigned*)&g3; unsigned* g4p = (unsigned*)&g4;
        #pragma unroll
        for (int i = 0; i < 4; ++i) {
            const float a0 = lo2f(ap[i]), a1 = hi2f(ap[i]);
            const float c0 = lo2f(cp[i]), c1 = hi2f(cp[i]);
            g1p[i] = pk2(a0 - c0, a1 - c1) & 0x7FFF7FFFu;
            g2p[i] = pk2(a0 + c0, a1 + c1);
            const float b0 = lo2f(bp[i]), b1 = hi2f(bp[i]);
            const float d0 = lo2f(dp[i]), d1 = hi2f(dp[i]);
            g3p[i] = pk2(b0 - d0, b1 - d1) & 0x7FFF7FFFu;
            g4p[i] = pk2(b0 + d0, b1 + d1);
        }
        u16* w = aw + (size_t)(base + h * 16) * 8;
        *(uint4*)(w)           = xv;   // g0, ks = 0..1
        *(uint4*)(w + 128 * 8) = g1;   // g1, ks = 2..3
        *(uint4*)(w + 256 * 8) = g2;   // g2, ks = 4..5
        *(uint4*)(w + 384 * 8) = g3;   // g3, ks = 6..7
        *(uint4*)(w + 512 * 8) = g4;   // g4, ks = 8..9
    }
}

// ---------------------------------------------------------------------------
// Layers 1..2 (and 3 in fallback): per-wave 16-edge tile, barrier-free.
// Per-wave LDS region 5120 u16 (10 KB): afrag[10][64][8]; ebuf reuses it.
// ---------------------------------------------------------------------------
__global__ __launch_bounds__(256, 4) void layer_mfma(
    const u16* __restrict__ xin, const int* __restrict__ nbr,
    const u16* __restrict__ wf, const float* __restrict__ bias,
    const float* __restrict__ lng, const float* __restrict__ lnb,
    u16* __restrict__ xout)
{
    __shared__ u16 lds[4 * 5120];            // 40 KB
    const int t  = threadIdx.x;
    const int l  = t & 63;
    const int wv = t >> 6;
    u16* aw = lds + wv * 5120;
    const int el = l >> 2, cq = l & 3;
    const int e0w = blockIdx.x * 64 + wv * 16;

    uint4 xv0, xv1;
    gather_pack16(xin, nbr, aw, e0w, el, cq, xv0, xv1);
    WAVE_SYNC();

    f32x4 ac0 = {}, ac1 = {}, ac2 = {}, ac3 = {};
    #pragma unroll
    for (int ks = 0; ks < 10; ++ks) {
        const bf16x8 a8 = *(const bf16x8*)(aw + (size_t)(ks * 64 + l) * 8);
        const u16* bk = wf + (size_t)(ks * 256 + l) * 8;
        ac0 = __builtin_amdgcn_mfma_f32_16x16x32_bf16(a8, *(const bf16x8*)(bk       ), ac0, 0, 0, 0);
        ac1 = __builtin_amdgcn_mfma_f32_16x16x32_bf16(a8, *(const bf16x8*)(bk +  512), ac1, 0, 0, 0);
        ac2 = __builtin_amdgcn_mfma_f32_16x16x32_bf16(a8, *(const bf16x8*)(bk + 1024), ac2, 0, 0, 0);
        ac3 = __builtin_amdgcn_mfma_f32_16x16x32_bf16(a8, *(const bf16x8*)(bk + 1536), ac3, 0, 0, 0);
    }
    WAVE_SYNC();   // drain A-frag reads before ebuf overwrites

    float* ew = (float*)aw;                  // 16 x 67 f32 = 4288 B
    const int colb = l & 15, rb = (l >> 4) * 4;
    {
        const float b0 = bias[colb],      b1 = bias[16 + colb];
        const float b2 = bias[32 + colb], b3 = bias[48 + colb];
        #pragma unroll
        for (int r = 0; r < 4; ++r) {
            float* er = ew + (rb + r) * 67;
            er[colb]      = ac0[r] + b0;  er[16 + colb] = ac1[r] + b1;
            er[32 + colb] = ac2[r] + b2;  er[48 + colb] = ac3[r] + b3;
        }
    }
    WAVE_SYNC();

    {   // ---- LN + ReLU + residual -> xout ----
        float lgv[16], lbv[16];
        #pragma unroll
        for (int j = 0; j < 4; ++j) {
            *(float4*)&lgv[j * 4] = *(const float4*)(lng + cq * 16 + j * 4);
            *(float4*)&lbv[j * 4] = *(const float4*)(lnb + cq * 16 + j * 4);
        }
        const float* rp = ew + el * 67 + cq * 16;
        float v[16];
        float s = 0.f, qs = 0.f;
        #pragma unroll
        for (int i = 0; i < 16; ++i) { v[i] = rp[i]; s += v[i]; qs += v[i] * v[i]; }
        s  += __shfl_xor(s, 1);  s  += __shfl_xor(s, 2);
        qs += __shfl_xor(qs, 1); qs += __shfl_xor(qs, 2);
        const float mu   = s * (1.f / 64.f);
        const float var  = qs * (1.f / 64.f) - mu * mu;
        const float rinv = rsqrtf(var + LN_EPS);
        const size_t e   = (size_t)e0w + el;
        u16* outp        = xout + e * 64 + cq * 16;
        #pragma unroll
        for (int h = 0; h < 2; ++h) {
            const uint4 res = h ? xv1 : xv0;
            const unsigned* rr = (const unsigned*)&res;
            uint4 o; unsigned* op = (unsigned*)&o;
            #pragma unroll
            for (int i = 0; i < 4; ++i) {
                const int k = h * 8 + i * 2;
                const float y0 = fmaxf(fmaf((v[k]   - mu) * rinv, lgv[k],   lbv[k]),   0.f) + lo2f(rr[i]);
                const float y1 = fmaxf(fmaf((v[k+1] - mu) * rinv, lgv[k+1], lbv[k+1]), 0.f) + hi2f(rr[i]);
                op[i] = pk2(y0, y1);
            }
            *(uint4*)(outp + h * 8) = o;
        }
    }
}

// ---------------------------------------------------------------------------
// Layer 3 fused with head, barrier-free per-wave version.
// y (bf16) is re-packed into frag layout in a disjoint sub-region (yb),
// then GEMM2 (2 MFMAs) + 16-lane shuffle row-sum -> logits. No hbuf.
// ---------------------------------------------------------------------------
__global__ __launch_bounds__(256, 4) void layer_head_mfma(
    const u16* __restrict__ xin, const int* __restrict__ nbr,
    const u16* __restrict__ wf, const float* __restrict__ bias,
    const float* __restrict__ lng, const float* __restrict__ lnb,
    const u16* __restrict__ wfh, const float* __restrict__ cb1,
    const float* __restrict__ cw2, const float* __restrict__ cb2,
    float* __restrict__ out)
{
    __shared__ u16 lds[4 * 5120];            // 40 KB
    const int t  = threadIdx.x;
    const int l  = t & 63;
    const int wv = t >> 6;
    u16* aw = lds + wv * 5120;
    u16* yb = aw + 2176;                     // past ebuf (2144 u16), 1024 u16
    const int el = l >> 2, cq = l & 3;
    const int e0w = blockIdx.x * 64 + wv * 16;

    uint4 xv0, xv1;
    gather_pack16(xin, nbr, aw, e0w, el, cq, xv0, xv1);
    WAVE_SYNC();

    f32x4 ac0 = {}, ac1 = {}, ac2 = {}, ac3 = {};
    #pragma unroll
    for (int ks = 0; ks < 10; ++ks) {
        const bf16x8 a8 = *(const bf16x8*)(aw + (size_t)(ks * 64 + l) * 8);
        const u16* bk = wf + (size_t)(ks * 256 + l) * 8;
        ac0 = __builtin_amdgcn_mfma_f32_16x16x32_bf16(a8, *(const bf16x8*)(bk       ), ac0, 0, 0, 0);
        ac1 = __builtin_amdgcn_mfma_f32_16x16x32_bf16(a8, *(const bf16x8*)(bk +  512), ac1, 0, 0, 0);
        ac2 = __builtin_amdgcn_mfma_f32_16x16x32_bf16(a8, *(const bf16x8*)(bk + 1024), ac2, 0, 0, 0);
        ac3 = __builtin_amdgcn_mfma_f32_16x16x32_bf16(a8, *(const bf16x8*)(bk + 1536), ac3, 0, 0, 0);
    }
    WAVE_SYNC();

    float* ew = (float*)aw;
    const int colb = l & 15, rb = (l >> 4) * 4;
    {
        const float b0 = bias[colb],      b1 = bias[16 + colb];
        const float b2 = bias[32 + colb], b3 = bias[48 + colb];
        #pragma unroll
        for (int r = 0; r < 4; ++r) {
            float* er = ew + (rb + r) * 67;
            er[colb]      = ac0[r] + b0;  er[16 + colb] = ac1[r] + b1;
            er[32 + colb] = ac2[r] + b2;  er[48 + colb] = ac3[r] + b3;
        }
    }
    WAVE_SYNC();

    {   // ---- LN + ReLU + residual -> y (bf16) -> yb in frag layout ----
        float lgv[16], lbv[16];
        #pragma unroll
        for (int j = 0; j < 4; ++j) {
            *(float4*)&lgv[j * 4] = *(const float4*)(lng + cq * 16 + j * 4);
            *(float4*)&lbv[j * 4] = *(const float4*)(lnb + cq * 16 + j * 4);
        }
        const float* rp = ew + el * 67 + cq * 16;
        float v[16];
        float s = 0.f, qs = 0.f;
        #pragma unroll
        for (int i = 0; i < 16; ++i) { v[i] = rp[i]; s += v[i]; qs += v[i] * v[i]; }
        s  += __shfl_xor(s, 1);  s  += __shfl_xor(s, 2);
        qs += __shfl_xor(qs, 1); qs += __shfl_xor(qs, 2);
        const float mu   = s * (1.f / 64.f);
        const float var  = qs * (1.f / 64.f) - mu * mu;
        const float rinv = rsqrtf(var + LN_EPS);
        const int ybase = (cq >> 1) * 64 + (cq & 1) * 32 + el;
        #pragma unroll
        for (int h = 0; h < 2; ++h) {
            const uint4 res = h ? xv1 : xv0;
            const unsigned* rr = (const unsigned*)&res;
            uint4 o; unsigned* op = (unsigned*)&o;
            #pragma unroll
            for (int i = 0; i < 4; ++i) {
                const int k = h * 8 + i * 2;
                const float y0 = fmaxf(fmaf((v[k]   - mu) * rinv, lgv[k],   lbv[k]),   0.f) + lo2f(rr[i]);
                const float y1 = fmaxf(fmaf((v[k+1] - mu) * rinv, lgv[k+1], lbv[k+1]), 0.f) + hi2f(rr[i]);
                op[i] = pk2(y0, y1);
            }
            *(uint4*)(yb + (size_t)(ybase + h * 16) * 8) = o;
        }
    }
    WAVE_SYNC();

    // ---- GEMM2: y(16x64) @ cw1(64x32) -> relu -> *cw2 -> row-sum ----
    f32x4 h0 = {}, h1 = {};
    #pragma unroll
    for (int ks = 0; ks < 2; ++ks) {
        const bf16x8 a8 = *(const bf16x8*)(yb + (size_t)(ks * 64 + l) * 8);
        const u16* bk = wfh + (size_t)(ks * 128 + l) * 8;
        h0 = __builtin_amdgcn_mfma_f32_16x16x32_bf16(a8, *(const bf16x8*)(bk      ), h0, 0, 0, 0);
        h1 = __builtin_amdgcn_mfma_f32_16x16x32_bf16(a8, *(const bf16x8*)(bk + 512), h1, 0, 0, 0);
    }
    {
        const float q1 = cb1[colb], q2 = cb1[16 + colb];
        const float w1 = cw2[colb], w2 = cw2[16 + colb];
        float sr[4];
        #pragma unroll
        for (int r = 0; r < 4; ++r)
            sr[r] = fmaxf(h0[r] + q1, 0.f) * w1 + fmaxf(h1[r] + q2, 0.f) * w2;
        #pragma unroll
        for (int m = 1; m < 16; m <<= 1) {
            #pragma unroll
            for (int r = 0; r < 4; ++r) sr[r] += __shfl_xor(sr[r], m);
        }
        if (colb == 0) {
            const float b2v = cb2[0];
            #pragma unroll
            for (int r = 0; r < 4; ++r) out[e0w + rb + r] = sr[r] + b2v;
        }
    }
}

// ---------------------------------------------------------------------------
// Standalone head (fallback path when workspace can't hold W-frags).
// Self-contained 32x32 path, unchanged.
// ---------------------------------------------------------------------------
__global__ __launch_bounds__(256) void head_mfma(
    const u16* __restrict__ xin,
    const float* __restrict__ cw1, const float* __restrict__ cb1,
    const float* __restrict__ cw2, const float* __restrict__ cb2,
    float* __restrict__ out)
{
    typedef float f32x16 __attribute__((ext_vector_type(16)));
    __shared__ float hbuf[4][32 * 33];
    const int t    = threadIdx.x;
    const int l    = t & 63;
    const int wv   = t >> 6;
    const int col  = l & 31;
    const int half = l >> 5;

    bf16x8 bf[4];
    #pragma unroll
    for (int ks = 0; ks < 4; ++ks) {
        const int kb = ks * 16 + half * 8;
        uint4 pk;
        pk.x = pk2(cw1[(kb+0)*32 + col], cw1[(kb+1)*32 + col]);
        pk.y = pk2(cw1[(kb+2)*32 + col], cw1[(kb+3)*32 + col]);
        pk.z = pk2(cw1[(kb+4)*32 + col], cw1[(kb+5)*32 + col]);
        pk.w = pk2(cw1[(kb+6)*32 + col], cw1[(kb+7)*32 + col]);
        __builtin_memcpy(&bf[ks], &pk, 16);
    }
    const float bc = cb1[col];
    const float w2 = cw2[col];
    const float b2 = cb2[0];

    int tile = blockIdx.x * 4 + wv;
    const int valid = tile < (E_EDGES / 32);
    if (!valid) tile = E_EDGES / 32 - 1;
    const size_t e0 = (size_t)tile * 32;
    const u16* xb = xin + (e0 + col) * 64 + half * 8;
    f32x16 acc = {};
    #pragma unroll
    for (int ks = 0; ks < 4; ++ks) {
        const bf16x8 a8 = *(const bf16x8*)(xb + ks * 16);
        acc = __builtin_amdgcn_mfma_f32_32x32x16_bf16(a8, bf[ks], acc, 0, 0, 0);
    }
    float* hb = hbuf[wv];
    #pragma unroll
    for (int r = 0; r < 16; ++r) {
        const int row = (r & 3) + 8 * (r >> 2) + 4 * half;
        hb[row * 33 + col] = fmaxf(acc[r] + bc, 0.f) * w2;
    }
    __syncthreads();
    const int row2 = l >> 1, part = l & 1;
    const float* rp = hb + row2 * 33 + part * 16;
    float s = 0.f;
    #pragma unroll
    for (int i = 0; i < 16; ++i) s += rp[i];
    s += __shfl_xor(s, 1);
    if (valid && part == 0) out[e0 + row2] = s + b2;
}

// ---------------------------------------------------------------------------
extern "C" void kernel_launch(void* const* d_in, const int* in_sizes, int n_in,
                              void* d_out, int out_size, void* d_ws, size_t ws_size,
                              hipStream_t stream)
{
    (void)in_sizes; (void)n_in; (void)out_size;
    const float* x   = (const float*)d_in[0];
    const int*   nbr = (const int*)d_in[1];
    const float* w0  = (const float*)d_in[2];
    const float* b0  = (const float*)d_in[3];
    const float* wr  = (const float*)d_in[4];
    const float* br  = (const float*)d_in[5];
    const float* lg  = (const float*)d_in[6];
    const float* lb  = (const float*)d_in[7];
    const float* cw1 = (const float*)d_in[8];
    const float* cb1 = (const float*)d_in[9];
    const float* cw2 = (const float*)d_in[10];
    const float* cb2 = (const float*)d_in[11];
    float* out = (float*)d_out;

    u16* xa = (u16*)d_ws;                         // E*64 bf16 = 128e6 B
    u16* xb = xa + (size_t)E_EDGES * 64;          // E*64 bf16 = 128e6 B
    u16* xc = xb;                                 // 32 MB, dead until layer1 writes xb

    const size_t act_bytes = 2ull * E_EDGES * 64 * 2;        // 256e6
    const size_t wf_bytes  = 8448ull * 16;                   // 135168
    const bool fused = (ws_size >= act_bytes + wf_bytes);
    u16* wfrag = fused ? (u16*)((char*)d_ws + act_bytes) : (u16*)d_out;

    const dim3 blk(256);
    wconv_kernel<<<dim3(33), blk, 0, stream>>>(wr, w0, cw1, wfrag);
    xprep_kernel<<<dim3((E_EDGES + 255) / 256), blk, 0, stream>>>(x, xc);
    layer0_mfma<<<dim3(E_EDGES / 64), blk, 0, stream>>>(xc, nbr, wfrag + 3*20480, b0, lg, lb, xa);
    layer_mfma<<<dim3(E_EDGES / 64), blk, 0, stream>>>(xa, nbr, wfrag,         br,       lg + 64,  lb + 64,  xb);
    layer_mfma<<<dim3(E_EDGES / 64), blk, 0, stream>>>(xb, nbr, wfrag + 20480, br + 64,  lg + 128, lb + 128, xa);
    if (fused) {
        layer_head_mfma<<<dim3(E_EDGES / 64), blk, 0, stream>>>(
            xa, nbr, wfrag + 40960, br + 128, lg + 192, lb + 192,
            wfrag + 65536, cb1, cw2, cb2, out);
    } else {
        layer_mfma<<<dim3(E_EDGES / 64), blk, 0, stream>>>(xa, nbr, wfrag + 40960,
            br + 128, lg + 192, lb + 192, xb);
        head_mfma<<<dim3((E_EDGES / 32 + 3) / 4), blk, 0, stream>>>(xb, cw1, cb1, cw2, cb2, out);
    }
}